// Round 1
// baseline (1445.089 us; speedup 1.0000x reference)
//
#include <hip/hip_runtime.h>

#define NNODES 50000
#define NEDGES 800000

typedef __bf16 bf16x8 __attribute__((ext_vector_type(8)));
typedef short short8 __attribute__((ext_vector_type(8)));
typedef float f32x4 __attribute__((ext_vector_type(4)));

// ws layout (shorts): fe_W0t[256][320] @0, fe_W1t[256][256] @81920,
// fe_W2t[128][256] @147456, fn_W0t[256][256] @180224, fn_W1t[256][256] @245760,
// fn_W2t[128][256] @311296. Then f32 node accumulator @ byte 688128.
#define OFF_FE_W0T 0
#define OFF_FE_W1T 81920
#define OFF_FE_W2T 147456
#define OFF_FN_W0T 180224
#define OFF_FN_W1T 245760
#define OFF_FN_W2T 311296
#define OFF_ACC_BYTES 688128

__device__ __forceinline__ short f2bf(float f) {
  union { float f; unsigned u; } v; v.f = f;
  unsigned r = v.u + 0x7FFFu + ((v.u >> 16) & 1u);   // RNE
  return (short)(r >> 16);
}

__device__ __forceinline__ void zero_acc(f32x4 acc[4][4]) {
#pragma unroll
  for (int m = 0; m < 4; ++m)
#pragma unroll
    for (int n = 0; n < 4; ++n)
      acc[m][n] = (f32x4){0.f, 0.f, 0.f, 0.f};
}

// One fused GEMM layer: A = LDS tile [128][K] bf16 (XOR-swizzled rows),
// B = global Wt [N][K] bf16 (transposed weights, L2-resident).
// Wave (wm,wn) computes rows wm*64..+63, cols wn*(NREP*16)..+NREP*16-1.
template <int KSTEPS, int NREP, int LDB, int WTK>
__device__ __forceinline__ void gemm_layer(const short* lds, const short* Wt,
                                           int wm, int wn, int lane,
                                           f32x4 acc[4][4]) {
  const int m0 = lane & 15;
  const int g = lane >> 4;
#pragma unroll
  for (int ks = 0; ks < KSTEPS; ++ks) {
    const int kb = ks * 32 + g * 8;
    bf16x8 a[4];
#pragma unroll
    for (int m = 0; m < 4; ++m) {
      int row = wm * 64 + m * 16 + m0;
      int byte = row * LDB + kb * 2;
      byte ^= (row & 7) << 4;
      a[m] = *(const bf16x8*)((const char*)lds + byte);
    }
#pragma unroll
    for (int n = 0; n < NREP; ++n) {
      int col = wn * (NREP * 16) + n * 16 + m0;
      bf16x8 b = *(const bf16x8*)(Wt + col * WTK + kb);
#pragma unroll
      for (int m = 0; m < 4; ++m)
        acc[m][n] = __builtin_amdgcn_mfma_f32_16x16x32_bf16(a[m], b, acc[m][n], 0, 0, 0);
    }
  }
}

// bias + relu + bf16 + write back to LDS [128][256] (swizzled) for the next layer.
template <int NREP, int LDB>
__device__ __forceinline__ void store_h(short* lds, const float* __restrict__ bias,
                                        int wm, int wn, int lane, f32x4 acc[4][4]) {
  const int m0 = lane & 15;
  const int g = lane >> 4;
#pragma unroll
  for (int n = 0; n < NREP; ++n) {
    int col = wn * (NREP * 16) + n * 16 + m0;
    float bv = bias[col];
#pragma unroll
    for (int m = 0; m < 4; ++m) {
#pragma unroll
      for (int j = 0; j < 4; ++j) {
        int row = wm * 64 + m * 16 + g * 4 + j;
        float v = acc[m][n][j] + bv;
        v = fmaxf(v, 0.f);
        int byte = row * LDB + col * 2;
        byte ^= (row & 7) << 4;
        *(short*)((char*)lds + byte) = f2bf(v);
      }
    }
  }
}

// Transpose+cast all 6 weight matrices f32 [K][N] -> bf16 [N][K] into ws.
__global__ void prep_weights_all(const float* __restrict__ w0, const float* __restrict__ w1,
                                 const float* __restrict__ w2, const float* __restrict__ w3,
                                 const float* __restrict__ w4, const float* __restrict__ w5,
                                 short* __restrict__ wsw) {
  const float* src; short* dst; int K, N;
  switch (blockIdx.y) {
    case 0: src = w0; dst = wsw + OFF_FE_W0T; K = 320; N = 256; break;
    case 1: src = w1; dst = wsw + OFF_FE_W1T; K = 256; N = 256; break;
    case 2: src = w2; dst = wsw + OFF_FE_W2T; K = 256; N = 128; break;
    case 3: src = w3; dst = wsw + OFF_FN_W0T; K = 256; N = 256; break;
    case 4: src = w4; dst = wsw + OFF_FN_W1T; K = 256; N = 256; break;
    default: src = w5; dst = wsw + OFF_FN_W2T; K = 256; N = 128; break;
  }
  int idx = blockIdx.x * 256 + threadIdx.x;
  if (idx < K * N) {
    int k = idx / N;
    int n = idx - k * N;
    dst[n * K + k] = f2bf(src[idx]);
  }
}

// Fused 3-layer edge MLP over a 128-edge tile + atomic segment-sum.
__global__ __launch_bounds__(512, 4) void edge_kernel(
    const float* __restrict__ node_attrs, const float* __restrict__ edge_attrs,
    const int* __restrict__ senders, const int* __restrict__ receivers,
    const short* __restrict__ wsw, float* __restrict__ acc_nodes,
    const float* __restrict__ b0, const float* __restrict__ b1,
    const float* __restrict__ b2, float* __restrict__ e_out) {
  __shared__ short lds[40960];  // 80 KiB: [128][320] bf16 for L0, reused [128][256] after
  const int tid = threadIdx.x;
  const int lane = tid & 63;
  const int wid = tid >> 6;
  const int wm = wid >> 2, wn = wid & 3;
  const int e0 = blockIdx.x * 128;

  // ---- stage X = [ns(128) | nr(128) | ea(64)] as bf16 [128][320], swizzled ----
#pragma unroll
  for (int i = 0; i < 10; ++i) {
    int task = i * 512 + tid;       // 5120 16B-chunks
    int row = task / 40;
    int c = task - row * 40;
    int erow = e0 + row;
    const float* p;
    if (c < 16)      p = node_attrs + (size_t)senders[erow] * 128 + c * 8;
    else if (c < 32) p = node_attrs + (size_t)receivers[erow] * 128 + (c - 16) * 8;
    else             p = edge_attrs + (size_t)erow * 64 + (c - 32) * 8;
    float4 v0 = *(const float4*)p;
    float4 v1 = *(const float4*)(p + 4);
    short8 pk;
    pk[0] = f2bf(v0.x); pk[1] = f2bf(v0.y); pk[2] = f2bf(v0.z); pk[3] = f2bf(v0.w);
    pk[4] = f2bf(v1.x); pk[5] = f2bf(v1.y); pk[6] = f2bf(v1.z); pk[7] = f2bf(v1.w);
    int byte = row * 640 + c * 16;
    byte ^= (row & 7) << 4;
    *(short8*)((char*)lds + byte) = pk;
  }
  __syncthreads();

  f32x4 acc[4][4];
  zero_acc(acc);
  gemm_layer<10, 4, 640, 320>(lds, wsw + OFF_FE_W0T, wm, wn, lane, acc);
  __syncthreads();
  store_h<4, 512>(lds, b0, wm, wn, lane, acc);
  __syncthreads();

  zero_acc(acc);
  gemm_layer<8, 4, 512, 256>(lds, wsw + OFF_FE_W1T, wm, wn, lane, acc);
  __syncthreads();
  store_h<4, 512>(lds, b1, wm, wn, lane, acc);
  __syncthreads();

  zero_acc(acc);
  gemm_layer<8, 2, 512, 256>(lds, wsw + OFF_FE_W2T, wm, wn, lane, acc);

  // ---- epilogue: e_out store + atomic segment-sum into node accumulator ----
  const int m0 = lane & 15;
  const int g = lane >> 4;
#pragma unroll
  for (int n = 0; n < 2; ++n) {
    int col = wn * 32 + n * 16 + m0;
    float bv = b2[col];
#pragma unroll
    for (int m = 0; m < 4; ++m) {
#pragma unroll
      for (int j = 0; j < 4; ++j) {
        int row = wm * 64 + m * 16 + g * 4 + j;
        int erow = e0 + row;
        float v = acc[m][n][j] + bv;
        e_out[(size_t)erow * 128 + col] = v;
        atomicAdd(&acc_nodes[(size_t)receivers[erow] * 128 + col], v);
      }
    }
  }
}

// Fused 3-layer node MLP over a 128-node tile.
__global__ __launch_bounds__(512, 4) void node_kernel(
    const float* __restrict__ node_attrs, const float* __restrict__ accn,
    const short* __restrict__ wsw,
    const float* __restrict__ b0, const float* __restrict__ b1,
    const float* __restrict__ b2, float* __restrict__ n_out) {
  __shared__ short lds[32768];  // 64 KiB: [128][256] bf16
  const int tid = threadIdx.x;
  const int lane = tid & 63;
  const int wid = tid >> 6;
  const int wm = wid >> 2, wn = wid & 3;
  const int r0 = blockIdx.x * 128;

  // ---- stage X = [node_attrs(128) | in_edges(128)] as bf16 [128][256], swizzled ----
#pragma unroll
  for (int i = 0; i < 8; ++i) {
    int task = i * 512 + tid;     // 4096 16B-chunks
    int row = task >> 5;
    int c = task & 31;
    int nrow = r0 + row;
    if (nrow >= NNODES) nrow = NNODES - 1;   // tail clamp (stores predicated later)
    const float* p = (c < 16) ? node_attrs + (size_t)nrow * 128 + c * 8
                              : accn + (size_t)nrow * 128 + (c - 16) * 8;
    float4 v0 = *(const float4*)p;
    float4 v1 = *(const float4*)(p + 4);
    short8 pk;
    pk[0] = f2bf(v0.x); pk[1] = f2bf(v0.y); pk[2] = f2bf(v0.z); pk[3] = f2bf(v0.w);
    pk[4] = f2bf(v1.x); pk[5] = f2bf(v1.y); pk[6] = f2bf(v1.z); pk[7] = f2bf(v1.w);
    int byte = row * 512 + c * 16;
    byte ^= (row & 7) << 4;
    *(short8*)((char*)lds + byte) = pk;
  }
  __syncthreads();

  f32x4 acc[4][4];
  zero_acc(acc);
  gemm_layer<8, 4, 512, 256>(lds, wsw + OFF_FN_W0T, wm, wn, lane, acc);
  __syncthreads();
  store_h<4, 512>(lds, b0, wm, wn, lane, acc);
  __syncthreads();

  zero_acc(acc);
  gemm_layer<8, 4, 512, 256>(lds, wsw + OFF_FN_W1T, wm, wn, lane, acc);
  __syncthreads();
  store_h<4, 512>(lds, b1, wm, wn, lane, acc);
  __syncthreads();

  zero_acc(acc);
  gemm_layer<8, 2, 512, 256>(lds, wsw + OFF_FN_W2T, wm, wn, lane, acc);

  const int m0 = lane & 15;
  const int g = lane >> 4;
#pragma unroll
  for (int n = 0; n < 2; ++n) {
    int col = wn * 32 + n * 16 + m0;
    float bv = b2[col];
#pragma unroll
    for (int m = 0; m < 4; ++m) {
#pragma unroll
      for (int j = 0; j < 4; ++j) {
        int row = wm * 64 + m * 16 + g * 4 + j;
        int grow = r0 + row;
        if (grow < NNODES) n_out[(size_t)grow * 128 + col] = acc[m][n][j] + bv;
      }
    }
  }
}

extern "C" void kernel_launch(void* const* d_in, const int* in_sizes, int n_in,
                              void* d_out, int out_size, void* d_ws, size_t ws_size,
                              hipStream_t stream) {
  const float* node_attrs = (const float*)d_in[0];
  const float* edge_attrs = (const float*)d_in[1];
  const int* senders = (const int*)d_in[2];
  const int* receivers = (const int*)d_in[3];
  const float* fe_W0 = (const float*)d_in[4];
  const float* fe_b0 = (const float*)d_in[5];
  const float* fe_W1 = (const float*)d_in[6];
  const float* fe_b1 = (const float*)d_in[7];
  const float* fe_W2 = (const float*)d_in[8];
  const float* fe_b2 = (const float*)d_in[9];
  const float* fn_W0 = (const float*)d_in[10];
  const float* fn_b0 = (const float*)d_in[11];
  const float* fn_W1 = (const float*)d_in[12];
  const float* fn_b1 = (const float*)d_in[13];
  const float* fn_W2 = (const float*)d_in[14];
  const float* fn_b2 = (const float*)d_in[15];

  short* wsw = (short*)d_ws;
  float* accn = (float*)((char*)d_ws + OFF_ACC_BYTES);
  float* out = (float*)d_out;
  float* n_out = out;                                  // [50000][128] first
  float* e_out = out + (size_t)NNODES * 128;           // then [800000][128]

  dim3 gprep(320, 6);
  prep_weights_all<<<gprep, 256, 0, stream>>>(fe_W0, fe_W1, fe_W2, fn_W0, fn_W1, fn_W2, wsw);
  hipMemsetAsync(accn, 0, (size_t)NNODES * 128 * sizeof(float), stream);

  edge_kernel<<<NEDGES / 128, 512, 0, stream>>>(node_attrs, edge_attrs, senders, receivers,
                                                wsw, accn, fe_b0, fe_b1, fe_b2, e_out);
  node_kernel<<<(NNODES + 127) / 128, 512, 0, stream>>>(node_attrs, accn, wsw,
                                                        fn_b0, fn_b1, fn_b2, n_out);
}

// Round 2
// 1393.377 us; speedup vs baseline: 1.0371x; 1.0371x over previous
//
#include <hip/hip_runtime.h>

#define NNODES 50000
#define NEDGES 800000

typedef __bf16 bf16x8 __attribute__((ext_vector_type(8)));
typedef short short8 __attribute__((ext_vector_type(8)));
typedef float f32x4 __attribute__((ext_vector_type(4)));

// ws layout: weights (shorts) then CSR arrays (ints). Byte offsets:
#define OFF_FE_W0T 0        // short idx
#define OFF_FE_W1T 81920
#define OFF_FE_W2T 147456
#define OFF_FN_W0T 180224
#define OFF_FN_W1T 245760
#define OFF_FN_W2T 311296   // + 32768 shorts -> ends at short 344064 = byte 688128
#define OFF_CNT_B    688128              // int[50000]
#define OFF_BASE_B   888128              // int[50001]
#define OFF_CURSOR_B 1088384             // int[50000]
#define OFF_EIDX_B   1288448             // int[800000] -> ends ~4.49 MB

__device__ __forceinline__ short f2bf(float f) {
  union { float f; unsigned u; } v; v.f = f;
  unsigned r = v.u + 0x7FFFu + ((v.u >> 16) & 1u);   // RNE
  return (short)(r >> 16);
}

__device__ __forceinline__ void zero_acc(f32x4 acc[4][4]) {
#pragma unroll
  for (int m = 0; m < 4; ++m)
#pragma unroll
    for (int n = 0; n < 4; ++n)
      acc[m][n] = (f32x4){0.f, 0.f, 0.f, 0.f};
}

// Fused GEMM layer with explicit B double-buffer (prefetch ks+1 before MFMAs of ks).
// A = LDS tile [128][K] bf16 (XOR-swizzled rows), B = global Wt [N][K] bf16 (L2-resident).
template <int KSTEPS, int NREP, int LDB, int WTK>
__device__ __forceinline__ void gemm_layer(const short* lds, const short* Wt,
                                           int wm, int wn, int lane,
                                           f32x4 acc[4][4]) {
  const int m0 = lane & 15;
  const int g = lane >> 4;
  const short* wp = Wt + (wn * (NREP * 16) + m0) * WTK + g * 8;
  bf16x8 bcur[NREP], bnxt[NREP], a[4];
#pragma unroll
  for (int n = 0; n < NREP; ++n) bcur[n] = *(const bf16x8*)(wp + n * 16 * WTK);
#pragma unroll
  for (int ks = 0; ks < KSTEPS; ++ks) {
    if (ks + 1 < KSTEPS) {
#pragma unroll
      for (int n = 0; n < NREP; ++n)
        bnxt[n] = *(const bf16x8*)(wp + (ks + 1) * 32 + n * 16 * WTK);
    }
    const int kb = ks * 32 + g * 8;
#pragma unroll
    for (int m = 0; m < 4; ++m) {
      int row = wm * 64 + m * 16 + m0;
      int byte = row * LDB + kb * 2;
      byte ^= (row & 7) << 4;
      a[m] = *(const bf16x8*)((const char*)lds + byte);
    }
#pragma unroll
    for (int n = 0; n < NREP; ++n)
#pragma unroll
      for (int m = 0; m < 4; ++m)
        acc[m][n] = __builtin_amdgcn_mfma_f32_16x16x32_bf16(a[m], bcur[n], acc[m][n], 0, 0, 0);
#pragma unroll
    for (int n = 0; n < NREP; ++n) bcur[n] = bnxt[n];
  }
}

// bias + relu + bf16 + write back to LDS (swizzled) for the next layer.
template <int NREP, int LDB>
__device__ __forceinline__ void store_h(short* lds, const float* __restrict__ bias,
                                        int wm, int wn, int lane, f32x4 acc[4][4]) {
  const int m0 = lane & 15;
  const int g = lane >> 4;
#pragma unroll
  for (int n = 0; n < NREP; ++n) {
    int col = wn * (NREP * 16) + n * 16 + m0;
    float bv = bias[col];
#pragma unroll
    for (int m = 0; m < 4; ++m) {
#pragma unroll
      for (int j = 0; j < 4; ++j) {
        int row = wm * 64 + m * 16 + g * 4 + j;
        float v = acc[m][n][j] + bv;
        v = fmaxf(v, 0.f);
        int byte = row * LDB + col * 2;
        byte ^= (row & 7) << 4;
        *(short*)((char*)lds + byte) = f2bf(v);
      }
    }
  }
}

// Transpose+cast all 6 weight matrices f32 [K][N] -> bf16 [N][K] into ws.
__global__ void prep_weights_all(const float* __restrict__ w0, const float* __restrict__ w1,
                                 const float* __restrict__ w2, const float* __restrict__ w3,
                                 const float* __restrict__ w4, const float* __restrict__ w5,
                                 short* __restrict__ wsw) {
  const float* src; short* dst; int K, N;
  switch (blockIdx.y) {
    case 0: src = w0; dst = wsw + OFF_FE_W0T; K = 320; N = 256; break;
    case 1: src = w1; dst = wsw + OFF_FE_W1T; K = 256; N = 256; break;
    case 2: src = w2; dst = wsw + OFF_FE_W2T; K = 256; N = 128; break;
    case 3: src = w3; dst = wsw + OFF_FN_W0T; K = 256; N = 256; break;
    case 4: src = w4; dst = wsw + OFF_FN_W1T; K = 256; N = 256; break;
    default: src = w5; dst = wsw + OFF_FN_W2T; K = 256; N = 128; break;
  }
  int idx = blockIdx.x * 256 + threadIdx.x;
  if (idx < K * N) {
    int k = idx / N;
    int n = idx - k * N;
    dst[n * K + k] = f2bf(src[idx]);
  }
}

// ---- CSR build: histogram -> scan -> scatter ----
__global__ void hist_kernel(const int* __restrict__ receivers, int* __restrict__ cnt) {
  int e = blockIdx.x * 512 + threadIdx.x;
  if (e < NEDGES) atomicAdd(&cnt[receivers[e]], 1);
}

__global__ __launch_bounds__(1024) void scan_kernel(const int* __restrict__ cnt,
                                                    int* __restrict__ base,
                                                    int* __restrict__ cursor) {
  __shared__ int s[1024];
  const int tid = threadIdx.x;
  int running = 0;
  const int nchunks = (NNODES + 1023) / 1024;
  for (int c = 0; c < nchunks; ++c) {
    int i = c * 1024 + tid;
    int v = (i < NNODES) ? cnt[i] : 0;
    s[tid] = v;
    __syncthreads();
    for (int off = 1; off < 1024; off <<= 1) {
      int t = (tid >= off) ? s[tid - off] : 0;
      __syncthreads();
      s[tid] += t;
      __syncthreads();
    }
    if (i < NNODES) {
      int excl = running + s[tid] - v;
      base[i] = excl;
      cursor[i] = excl;
    }
    running += s[1023];
    __syncthreads();
  }
  if (tid == 0) base[NNODES] = running;
}

__global__ void scatter_kernel(const int* __restrict__ receivers, int* __restrict__ cursor,
                               int* __restrict__ eidx) {
  int e = blockIdx.x * 512 + threadIdx.x;
  if (e < NEDGES) {
    int pos = atomicAdd(&cursor[receivers[e]], 1);
    eidx[pos] = e;
  }
}

// Fused 3-layer edge MLP over a 128-edge tile (no atomics; segment-sum moved to node kernel).
__global__ __launch_bounds__(512, 4) void edge_kernel(
    const float* __restrict__ node_attrs, const float* __restrict__ edge_attrs,
    const int* __restrict__ senders, const int* __restrict__ receivers,
    const short* __restrict__ wsw,
    const float* __restrict__ b0, const float* __restrict__ b1,
    const float* __restrict__ b2, float* __restrict__ e_out) {
  __shared__ short lds[40960];  // 80 KiB: [128][320] bf16 for L0, reused [128][256] after
  const int tid = threadIdx.x;
  const int lane = tid & 63;
  const int wid = tid >> 6;
  const int wm = wid >> 2, wn = wid & 3;
  const int e0 = blockIdx.x * 128;

  // ---- stage X = [ns(128) | nr(128) | ea(64)] as bf16 [128][320], swizzled ----
#pragma unroll
  for (int i = 0; i < 10; ++i) {
    int task = i * 512 + tid;       // 5120 16B-chunks
    int row = task / 40;
    int c = task - row * 40;
    int erow = e0 + row;
    const float* p;
    if (c < 16)      p = node_attrs + (size_t)senders[erow] * 128 + c * 8;
    else if (c < 32) p = node_attrs + (size_t)receivers[erow] * 128 + (c - 16) * 8;
    else             p = edge_attrs + (size_t)erow * 64 + (c - 32) * 8;
    float4 v0 = *(const float4*)p;
    float4 v1 = *(const float4*)(p + 4);
    short8 pk;
    pk[0] = f2bf(v0.x); pk[1] = f2bf(v0.y); pk[2] = f2bf(v0.z); pk[3] = f2bf(v0.w);
    pk[4] = f2bf(v1.x); pk[5] = f2bf(v1.y); pk[6] = f2bf(v1.z); pk[7] = f2bf(v1.w);
    int byte = row * 640 + c * 16;
    byte ^= (row & 7) << 4;
    *(short8*)((char*)lds + byte) = pk;
  }
  __syncthreads();

  f32x4 acc[4][4];
  zero_acc(acc);
  gemm_layer<10, 4, 640, 320>(lds, wsw + OFF_FE_W0T, wm, wn, lane, acc);
  __syncthreads();
  store_h<4, 512>(lds, b0, wm, wn, lane, acc);
  __syncthreads();

  zero_acc(acc);
  gemm_layer<8, 4, 512, 256>(lds, wsw + OFF_FE_W1T, wm, wn, lane, acc);
  __syncthreads();
  store_h<4, 512>(lds, b1, wm, wn, lane, acc);
  __syncthreads();

  zero_acc(acc);
  gemm_layer<8, 2, 512, 256>(lds, wsw + OFF_FE_W2T, wm, wn, lane, acc);

  const int m0 = lane & 15;
  const int g = lane >> 4;
#pragma unroll
  for (int n = 0; n < 2; ++n) {
    int col = wn * 32 + n * 16 + m0;
    float bv = b2[col];
#pragma unroll
    for (int m = 0; m < 4; ++m) {
#pragma unroll
      for (int j = 0; j < 4; ++j) {
        int row = wm * 64 + m * 16 + g * 4 + j;
        int erow = e0 + row;
        e_out[(size_t)erow * 128 + col] = acc[m][n][j] + bv;
      }
    }
  }
}

// Fused 3-layer node MLP over a 128-node tile; in_edges built by CSR gather-sum of e_out.
__global__ __launch_bounds__(512, 4) void node_kernel(
    const float* __restrict__ node_attrs, const float* __restrict__ e_out,
    const int* __restrict__ basep, const int* __restrict__ eidx,
    const short* __restrict__ wsw,
    const float* __restrict__ b0, const float* __restrict__ b1,
    const float* __restrict__ b2, float* __restrict__ n_out) {
  __shared__ short lds[32768];  // 64 KiB: [128][256] bf16
  const int tid = threadIdx.x;
  const int lane = tid & 63;
  const int wid = tid >> 6;
  const int wm = wid >> 2, wn = wid & 3;
  const int r0 = blockIdx.x * 128;

  // ---- stage node_attrs -> LDS cols 0..127 ----
#pragma unroll
  for (int i = 0; i < 4; ++i) {
    int task = i * 512 + tid;     // 2048 16B-chunks
    int row = task >> 4;
    int c = task & 15;
    int nrow = r0 + row;
    if (nrow >= NNODES) nrow = NNODES - 1;
    const float* p = node_attrs + (size_t)nrow * 128 + c * 8;
    float4 v0 = *(const float4*)p;
    float4 v1 = *(const float4*)(p + 4);
    short8 pk;
    pk[0] = f2bf(v0.x); pk[1] = f2bf(v0.y); pk[2] = f2bf(v0.z); pk[3] = f2bf(v0.w);
    pk[4] = f2bf(v1.x); pk[5] = f2bf(v1.y); pk[6] = f2bf(v1.z); pk[7] = f2bf(v1.w);
    int byte = row * 512 + c * 16;
    byte ^= (row & 7) << 4;
    *(short8*)((char*)lds + byte) = pk;
  }

  // ---- CSR gather-sum: in_edges -> LDS cols 128..255 ----
  {
    const int n_local = tid >> 2;       // 0..127
    const int cg = tid & 3;             // 32-col group
    const int node = r0 + n_local;
    float sum[32];
#pragma unroll
    for (int q = 0; q < 32; ++q) sum[q] = 0.f;
    if (node < NNODES) {
      int beg = basep[node], end = basep[node + 1];
      for (int j = beg; j < end; ++j) {
        int e = eidx[j];
        const float* er = e_out + (size_t)e * 128 + cg * 32;
#pragma unroll
        for (int q = 0; q < 8; ++q) {
          float4 v = *(const float4*)(er + q * 4);
          sum[q * 4 + 0] += v.x; sum[q * 4 + 1] += v.y;
          sum[q * 4 + 2] += v.z; sum[q * 4 + 3] += v.w;
        }
      }
    }
#pragma unroll
    for (int q = 0; q < 4; ++q) {
      short8 pk;
#pragma unroll
      for (int k = 0; k < 8; ++k) pk[k] = f2bf(sum[q * 8 + k]);
      int col = 128 + cg * 32 + q * 8;
      int byte = n_local * 512 + col * 2;
      byte ^= (n_local & 7) << 4;
      *(short8*)((char*)lds + byte) = pk;
    }
  }
  __syncthreads();

  f32x4 acc[4][4];
  zero_acc(acc);
  gemm_layer<8, 4, 512, 256>(lds, wsw + OFF_FN_W0T, wm, wn, lane, acc);
  __syncthreads();
  store_h<4, 512>(lds, b0, wm, wn, lane, acc);
  __syncthreads();

  zero_acc(acc);
  gemm_layer<8, 4, 512, 256>(lds, wsw + OFF_FN_W1T, wm, wn, lane, acc);
  __syncthreads();
  store_h<4, 512>(lds, b1, wm, wn, lane, acc);
  __syncthreads();

  zero_acc(acc);
  gemm_layer<8, 2, 512, 256>(lds, wsw + OFF_FN_W2T, wm, wn, lane, acc);

  const int m0 = lane & 15;
  const int g = lane >> 4;
#pragma unroll
  for (int n = 0; n < 2; ++n) {
    int col = wn * 32 + n * 16 + m0;
    float bv = b2[col];
#pragma unroll
    for (int m = 0; m < 4; ++m) {
#pragma unroll
      for (int j = 0; j < 4; ++j) {
        int row = wm * 64 + m * 16 + g * 4 + j;
        int grow = r0 + row;
        if (grow < NNODES) n_out[(size_t)grow * 128 + col] = acc[m][n][j] + bv;
      }
    }
  }
}

extern "C" void kernel_launch(void* const* d_in, const int* in_sizes, int n_in,
                              void* d_out, int out_size, void* d_ws, size_t ws_size,
                              hipStream_t stream) {
  const float* node_attrs = (const float*)d_in[0];
  const float* edge_attrs = (const float*)d_in[1];
  const int* senders = (const int*)d_in[2];
  const int* receivers = (const int*)d_in[3];
  const float* fe_W0 = (const float*)d_in[4];
  const float* fe_b0 = (const float*)d_in[5];
  const float* fe_W1 = (const float*)d_in[6];
  const float* fe_b1 = (const float*)d_in[7];
  const float* fe_W2 = (const float*)d_in[8];
  const float* fe_b2 = (const float*)d_in[9];
  const float* fn_W0 = (const float*)d_in[10];
  const float* fn_b0 = (const float*)d_in[11];
  const float* fn_W1 = (const float*)d_in[12];
  const float* fn_b1 = (const float*)d_in[13];
  const float* fn_W2 = (const float*)d_in[14];
  const float* fn_b2 = (const float*)d_in[15];

  short* wsw = (short*)d_ws;
  int* cnt    = (int*)((char*)d_ws + OFF_CNT_B);
  int* basep  = (int*)((char*)d_ws + OFF_BASE_B);
  int* cursor = (int*)((char*)d_ws + OFF_CURSOR_B);
  int* eidx   = (int*)((char*)d_ws + OFF_EIDX_B);
  float* out = (float*)d_out;
  float* n_out = out;                                  // [50000][128] first
  float* e_out = out + (size_t)NNODES * 128;           // then [800000][128]

  dim3 gprep(320, 6);
  prep_weights_all<<<gprep, 256, 0, stream>>>(fe_W0, fe_W1, fe_W2, fn_W0, fn_W1, fn_W2, wsw);
  hipMemsetAsync(cnt, 0, NNODES * sizeof(int), stream);

  hist_kernel<<<(NEDGES + 511) / 512, 512, 0, stream>>>(receivers, cnt);
  scan_kernel<<<1, 1024, 0, stream>>>(cnt, basep, cursor);
  scatter_kernel<<<(NEDGES + 511) / 512, 512, 0, stream>>>(receivers, cursor, eidx);

  edge_kernel<<<NEDGES / 128, 512, 0, stream>>>(node_attrs, edge_attrs, senders, receivers,
                                                wsw, fe_b0, fe_b1, fe_b2, e_out);
  node_kernel<<<(NNODES + 127) / 128, 512, 0, stream>>>(node_attrs, e_out, basep, eidx, wsw,
                                                        fn_b0, fn_b1, fn_b2, n_out);
}